// Round 2
// baseline (282.347 us; speedup 1.0000x reference)
//
#include <hip/hip_runtime.h>
#include <math.h>

#define HDIM 4096
#define NEXP 64
#define NTOK 8192
#define KSPLIT 8
#define KSLICE (HDIM / KSPLIT)   // 512
#define BM 128
#define CHUNK 32
#define NCHUNK (KSLICE / CHUNK)  // 16
#define AROW 36                  // fp32 per LDS A row: 32 data + 4 pad = 144B (uniform banks)
#define PSTRIDE 2048             // shorts: one (chunk,part) plane = 64 experts * 32 k
#define CSTRIDE 6144             // shorts: 3 parts per chunk
#define AUXF 1024                // floats reserved for auxbuf copies
#define BSF 393216               // floats holding 786432 shorts of pre-split B (3*64*4096)
#define SLICEOFF (AUXF + BSF)    // slices start here (floats)
#define TPW 2

typedef short short8 __attribute__((ext_vector_type(8)));
typedef float f32x4 __attribute__((ext_vector_type(4)));

// Exact 3-way bf16 split of two fp32 values, packed as (lo16=x0, hi16=x1).
// x = hi + mid + lo exactly (8+8+8 mantissa bits covers fp32's 24).
__device__ __forceinline__ void split2x3(float x0, float x1, int& h, int& md, int& lo) {
  unsigned u0 = __float_as_uint(x0), u1 = __float_as_uint(x1);
  unsigned h0 = u0 & 0xFFFF0000u, h1 = u1 & 0xFFFF0000u;
  float r0 = x0 - __uint_as_float(h0);
  float r1 = x1 - __uint_as_float(h1);
  unsigned m0 = __float_as_uint(r0) & 0xFFFF0000u;
  unsigned m1 = __float_as_uint(r1) & 0xFFFF0000u;
  float s0 = r0 - __uint_as_float(m0);
  float s1 = r1 - __uint_as_float(m1);
  h  = (int)((h0 >> 16) | h1);
  md = (int)((m0 >> 16) | m1);
  lo = (int)((__float_as_uint(s0) >> 16) | (__float_as_uint(s1) & 0xFFFF0000u));
}

__device__ __forceinline__ short8 pack_s8(int a, int b, int c, int d) {
  union { int i[4]; short8 s; } u;
  u.i[0] = a; u.i[1] = b; u.i[2] = c; u.i[3] = d;
  return u.s;
}

// ---------------------------------------------------------------------------
// Pre-split gate_w into bf16x3 planes, layout [chunk c][part][expert][32 k].
// 1.5 MB -> L2-resident; read directly as MFMA B-fragments by every gemm block
// (replaces per-block B conversion + B LDS staging: 512x redundant VALU gone).
// ---------------------------------------------------------------------------
__global__ void bsplit_k(const float* __restrict__ W, short* __restrict__ Bs) {
  const int e = blockIdx.x;      // 64 experts
  const int tid = threadIdx.x;   // 256
#pragma unroll
  for (int it = 0; it < 2; ++it) {
    const int k0 = tid * 16 + it * 8;  // 0..4088
    const float4 v0 = *(const float4*)&W[(size_t)e * HDIM + k0];
    const float4 v1 = *(const float4*)&W[(size_t)e * HDIM + k0 + 4];
    const float f[8] = {v0.x, v0.y, v0.z, v0.w, v1.x, v1.y, v1.z, v1.w};
    int h[4], md[4], lo[4];
#pragma unroll
    for (int j = 0; j < 4; ++j) split2x3(f[2 * j], f[2 * j + 1], h[j], md[j], lo[j]);
    const int c = k0 >> 5, kk = k0 & 31;
    short* p = Bs + (size_t)c * CSTRIDE + (size_t)e * 32 + kk;
    *(int4*)(p)               = make_int4(h[0], h[1], h[2], h[3]);
    *(int4*)(p + PSTRIDE)     = make_int4(md[0], md[1], md[2], md[3]);
    *(int4*)(p + 2 * PSTRIDE) = make_int4(lo[0], lo[1], lo[2], lo[3]);
  }
}

// ---------------------------------------------------------------------------
// GEMM v2: A staged as raw fp32 in LDS (double-buffered, 1 barrier/chunk),
// bf16x3 split done at fragment-read time (once per element per block).
// B fragments read directly from the L2-hot pre-split buffer — no B in LDS.
// LDS traffic/chunk/block: 108 KB -> 32 KB; ds instrs/wave/chunk: 27 -> 8.
// Numerics identical to the round-0 (passing) kernel.
// ---------------------------------------------------------------------------
__global__ __launch_bounds__(256, 3) void gemm_k(const float* __restrict__ A,
                                                 const short* __restrict__ Bs,
                                                 float* __restrict__ Lp,
                                                 int atomic_mode) {
  __shared__ __align__(16) float As[2][BM * AROW];  // 2 x 18 KB
  const int tid = threadIdx.x;
  const int m_base = blockIdx.x * BM;
  const int k_base = blockIdx.y * KSLICE;
  float* Lout = Lp + (atomic_mode ? (size_t)0 : (size_t)blockIdx.y * NTOK * NEXP);

  // staging: thread covers 16B slot (tid&7) of row (tid>>3) in 4 row-groups
  const int srow = tid >> 3;   // 0..31
  const int sslot = tid & 7;   // 0..7
  const float* gA = A + (size_t)(m_base + srow) * HDIM + k_base + sslot * 4;

  const int lane = tid & 63;
  const int wave = tid >> 6;
  const int l15 = lane & 15;
  const int quad = lane >> 4;
  const int wm = wave * 32;

  f32x4 acc[2][4];
#pragma unroll
  for (int mt = 0; mt < 2; ++mt)
#pragma unroll
    for (int nt = 0; nt < 4; ++nt) acc[mt][nt] = (f32x4){0.f, 0.f, 0.f, 0.f};

  float4 pre[4];
  auto gload = [&](int i) {
#pragma unroll
    for (int j = 0; j < 4; ++j)
      pre[j] = *(const float4*)(gA + (size_t)(j * 32) * HDIM + i * CHUNK);
  };
  auto stage = [&](int buf) {
#pragma unroll
    for (int j = 0; j < 4; ++j)
      *(float4*)&As[buf][(j * 32 + srow) * AROW + sslot * 4] = pre[j];
  };

  gload(0);
  stage(0);
  __syncthreads();

  // B fragment base: [cg][part][e=nt*16+l15][quad*8 ..]
  const short* bbase = Bs + (size_t)(k_base >> 5) * CSTRIDE + (size_t)l15 * 32 + quad * 8;

  for (int i = 0; i < NCHUNK; ++i) {
    if (i + 1 < NCHUNK) gload(i + 1);
    const int buf = i & 1;

    // A fragments: 2x ds_read_b128 per mt, split to bf16x3 in-register
    short8 fa[2][3];
#pragma unroll
    for (int mt = 0; mt < 2; ++mt) {
      const int r = (wm + mt * 16 + l15) * AROW + quad * 8;
      const float4 a0 = *(const float4*)&As[buf][r];
      const float4 a1 = *(const float4*)&As[buf][r + 4];
      const float f[8] = {a0.x, a0.y, a0.z, a0.w, a1.x, a1.y, a1.z, a1.w};
      int h[4], md[4], lo[4];
#pragma unroll
      for (int j = 0; j < 4; ++j) split2x3(f[2 * j], f[2 * j + 1], h[j], md[j], lo[j]);
      fa[mt][0] = pack_s8(h[0], h[1], h[2], h[3]);
      fa[mt][1] = pack_s8(md[0], md[1], md[2], md[3]);
      fa[mt][2] = pack_s8(lo[0], lo[1], lo[2], lo[3]);
    }

    const short* bp = bbase + (size_t)i * CSTRIDE;
#pragma unroll
    for (int nt = 0; nt < 4; ++nt) {
      const short8 bh = *(const short8*)(bp + nt * (16 * 32));
      const short8 bm = *(const short8*)(bp + nt * (16 * 32) + PSTRIDE);
      const short8 bl = *(const short8*)(bp + nt * (16 * 32) + 2 * PSTRIDE);
#pragma unroll
      for (int mt = 0; mt < 2; ++mt) {
        f32x4 c = acc[mt][nt];
        c = __builtin_amdgcn_mfma_f32_16x16x32_bf16(fa[mt][0], bh, c, 0, 0, 0);
        c = __builtin_amdgcn_mfma_f32_16x16x32_bf16(fa[mt][0], bm, c, 0, 0, 0);
        c = __builtin_amdgcn_mfma_f32_16x16x32_bf16(fa[mt][1], bh, c, 0, 0, 0);
        c = __builtin_amdgcn_mfma_f32_16x16x32_bf16(fa[mt][0], bl, c, 0, 0, 0);
        c = __builtin_amdgcn_mfma_f32_16x16x32_bf16(fa[mt][2], bh, c, 0, 0, 0);
        c = __builtin_amdgcn_mfma_f32_16x16x32_bf16(fa[mt][1], bm, c, 0, 0, 0);
        acc[mt][nt] = c;
      }
    }

    // write next chunk into the other buffer; single barrier per chunk:
    // reads of As[buf] (above) and writes of As[buf^1] (here) are separated
    // from their conflicting accesses by exactly one __syncthreads.
    if (i + 1 < NCHUNK) stage(buf ^ 1);
    __syncthreads();
  }

#pragma unroll
  for (int mt = 0; mt < 2; ++mt)
#pragma unroll
    for (int nt = 0; nt < 4; ++nt)
#pragma unroll
      for (int r = 0; r < 4; ++r) {
        const int m = m_base + wm + mt * 16 + quad * 4 + r;
        const int n = nt * 16 + l15;
        if (atomic_mode) atomicAdd(&Lout[(size_t)m * NEXP + n], acc[mt][nt][r]);
        else Lout[(size_t)m * NEXP + n] = acc[mt][nt][r];
      }
}

// ---------------------------------------------------------------------------
// Top-k router, wave-per-token (lane = expert). Unrolled 8-slice reduction
// (nsl is runtime -> compiler couldn't unroll; 8 serialized HBM latencies).
// ---------------------------------------------------------------------------
__global__ __launch_bounds__(256) void topk_k(const float* __restrict__ Lp, int nsl,
                                              float* __restrict__ out,
                                              float* __restrict__ auxbuf) {
  __shared__ float sl[4][64];
  __shared__ float s_aux[128];  // [0:64) prob sums, [64:128) pick counts
  const int tid = threadIdx.x;
  const int wave = tid >> 6, lane = tid & 63;
  if (tid < 128) s_aux[tid] = 0.f;
  __syncthreads();

  for (int it = 0; it < TPW; ++it) {
    const int t = (blockIdx.x * 4 + wave) * TPW + it;
    float x = 0.f;
    if (nsl == 8) {
#pragma unroll
      for (int s = 0; s < 8; ++s)
        x += Lp[(size_t)s * (NTOK * NEXP) + (size_t)t * NEXP + lane];
    } else {
      for (int s = 0; s < nsl; ++s)
        x += Lp[(size_t)s * (NTOK * NEXP) + (size_t)t * NEXP + lane];
    }
    sl[wave][lane] = x;

    float mx = x;
#pragma unroll
    for (int off = 32; off >= 1; off >>= 1)
      mx = fmaxf(mx, __shfl_xor(mx, off, 64));
    const float e = __expf(x - mx);
    float ssum = e;
#pragma unroll
    for (int off = 32; off >= 1; off >>= 1) ssum += __shfl_xor(ssum, off, 64);
    const float prob = e / ssum;

    __syncthreads();  // sl visible (uniform barrier: same trip count all waves)

    int cnt = 0;
#pragma unroll
    for (int c = 0; c < 4; ++c) {
      const float4 v0 = *(const float4*)&sl[wave][c * 16 + 0];
      const float4 v1 = *(const float4*)&sl[wave][c * 16 + 4];
      const float4 v2 = *(const float4*)&sl[wave][c * 16 + 8];
      const float4 v3 = *(const float4*)&sl[wave][c * 16 + 12];
      const float xv[16] = {v0.x, v0.y, v0.z, v0.w, v1.x, v1.y, v1.z, v1.w,
                            v2.x, v2.y, v2.z, v2.w, v3.x, v3.y, v3.z, v3.w};
#pragma unroll
      for (int j = 0; j < 16; ++j) {
        const int jj = c * 16 + j;
        cnt += (xv[j] > x) || (xv[j] == x && jj < lane);
      }
    }

    float tp = (cnt < 8) ? prob : 0.f;
    float tsum = tp;
#pragma unroll
    for (int off = 32; off >= 1; off >>= 1) tsum += __shfl_xor(tsum, off, 64);

    const int dst = cnt << 2;  // ranks are a permutation -> collision-free
    const float pv = __uint_as_float(
        (unsigned)__builtin_amdgcn_ds_permute(dst, (int)__float_as_uint(prob)));
    const int pi = __builtin_amdgcn_ds_permute(dst, lane);
    if (lane < 8) {
      out[(size_t)t * 8 + lane] = pv / tsum;
      out[(size_t)NTOK * 8 + (size_t)t * 8 + lane] = (float)pi;
    }
    atomicAdd(&s_aux[lane], prob);
    if (cnt < 8) atomicAdd(&s_aux[64 + lane], 1.f);
  }
  __syncthreads();
  if (tid < 128) atomicAdd(&auxbuf[(blockIdx.x & 7) * 128 + tid], s_aux[tid]);
}

// aux = E * sum_e (count_e/(T*K)) * (sumprob_e/T), over 8 auxbuf copies
__global__ void aux_k(const float* __restrict__ auxbuf, float* __restrict__ out) {
  const int e = threadIdx.x;  // 64 threads
  float p = 0.f, f = 0.f;
#pragma unroll
  for (int c = 0; c < 8; ++c) {
    p += auxbuf[c * 128 + e];
    f += auxbuf[c * 128 + 64 + e];
  }
  p *= (1.f / (float)NTOK);
  f *= (1.f / ((float)NTOK * 8.f));
  float v = f * p;
#pragma unroll
  for (int off = 32; off >= 1; off >>= 1) v += __shfl_xor(v, off, 64);
  if (e == 0) out[2 * NTOK * 8] = 64.f * v;
}

extern "C" void kernel_launch(void* const* d_in, const int* in_sizes, int n_in,
                              void* d_out, int out_size, void* d_ws, size_t ws_size,
                              hipStream_t stream) {
  const float* hidden = (const float*)d_in[0];  // 8192 x 4096 fp32
  const float* gate = (const float*)d_in[1];    // 64 x 4096 fp32
  float* out = (float*)d_out;                   // [w 65536 | idx 65536 | aux 1]
  float* ws = (float*)d_ws;
  float* auxbuf = ws;                        // 8 copies x 128 floats
  short* Bs = (short*)(ws + AUXF);           // pre-split B, 1.5 MB
  float* slices = ws + SLICEOFF;             // KSPLIT x (8192*64) fp32 partials

  const size_t need = (size_t)SLICEOFF * 4 + (size_t)KSPLIT * NTOK * NEXP * 4;
  const int atomic_mode = (ws_size < need) ? 1 : 0;
  const int nsl = atomic_mode ? 1 : KSPLIT;

  if (atomic_mode)
    hipMemsetAsync(d_ws, 0, (size_t)SLICEOFF * 4 + (size_t)NTOK * NEXP * 4, stream);
  else
    hipMemsetAsync(d_ws, 0, (size_t)AUXF * 4, stream);

  bsplit_k<<<NEXP, 256, 0, stream>>>(gate, Bs);
  gemm_k<<<dim3(64, KSPLIT), 256, 0, stream>>>(hidden, Bs, slices, atomic_mode);
  topk_k<<<NTOK / (4 * TPW), 256, 0, stream>>>(slices, nsl, out, auxbuf);
  aux_k<<<1, 64, 0, stream>>>(auxbuf, out);
}

// Round 3
// 227.851 us; speedup vs baseline: 1.2392x; 1.2392x over previous
//
#include <hip/hip_runtime.h>
#include <math.h>

#define HDIM 4096
#define NEXP 64
#define NTOK 8192
#define KSPLIT 16
#define KSLICE (HDIM / KSPLIT)   // 256
#define BM 128
#define CHUNK 32
#define NCHUNK (KSLICE / CHUNK)  // 8
#define PSTRIDE 2048             // shorts: one (chunk,part) plane = 64 experts * 32 k
#define CSTRIDE 6144             // shorts: 3 parts per chunk
#define AUXF 1024                // floats reserved for auxbuf copies
#define BSF 393216               // floats holding 786432 shorts of pre-split B (3*64*4096)
#define SLICEOFF (AUXF + BSF)    // slices start here (floats)
#define TPW 2

typedef short short8 __attribute__((ext_vector_type(8)));
typedef float f32x4 __attribute__((ext_vector_type(4)));
typedef const __attribute__((address_space(1))) unsigned int* gas_t;
typedef __attribute__((address_space(3))) unsigned int* las_t;

// Exact 3-way bf16 split of two fp32 values, packed as (lo16=x0, hi16=x1).
// x = hi + mid + lo exactly (8+8+8 mantissa bits covers fp32's 24).
__device__ __forceinline__ void split2x3(float x0, float x1, int& h, int& md, int& lo) {
  unsigned u0 = __float_as_uint(x0), u1 = __float_as_uint(x1);
  unsigned h0 = u0 & 0xFFFF0000u, h1 = u1 & 0xFFFF0000u;
  float r0 = x0 - __uint_as_float(h0);
  float r1 = x1 - __uint_as_float(h1);
  unsigned m0 = __float_as_uint(r0) & 0xFFFF0000u;
  unsigned m1 = __float_as_uint(r1) & 0xFFFF0000u;
  float s0 = r0 - __uint_as_float(m0);
  float s1 = r1 - __uint_as_float(m1);
  h  = (int)((h0 >> 16) | h1);
  md = (int)((m0 >> 16) | m1);
  lo = (int)((__float_as_uint(s0) >> 16) | (__float_as_uint(s1) & 0xFFFF0000u));
}

__device__ __forceinline__ short8 pack_s8(int a, int b, int c, int d) {
  union { int i[4]; short8 s; } u;
  u.i[0] = a; u.i[1] = b; u.i[2] = c; u.i[3] = d;
  return u.s;
}

// ---------------------------------------------------------------------------
// Pre-split gate_w into bf16x3 planes, layout [chunk c][part][expert][32 k].
// 1.5 MB -> L2-resident; read directly as MFMA B-fragments by every gemm block.
// ---------------------------------------------------------------------------
__global__ void bsplit_k(const float* __restrict__ W, short* __restrict__ Bs) {
  const int e = blockIdx.x;      // 64 experts
  const int tid = threadIdx.x;   // 256
#pragma unroll
  for (int it = 0; it < 2; ++it) {
    const int k0 = tid * 16 + it * 8;  // 0..4088
    const float4 v0 = *(const float4*)&W[(size_t)e * HDIM + k0];
    const float4 v1 = *(const float4*)&W[(size_t)e * HDIM + k0 + 4];
    const float f[8] = {v0.x, v0.y, v0.z, v0.w, v1.x, v1.y, v1.z, v1.w};
    int h[4], md[4], lo[4];
#pragma unroll
    for (int j = 0; j < 4; ++j) split2x3(f[2 * j], f[2 * j + 1], h[j], md[j], lo[j]);
    const int c = k0 >> 5, kk = k0 & 31;
    short* p = Bs + (size_t)c * CSTRIDE + (size_t)e * 32 + kk;
    *(int4*)(p)               = make_int4(h[0], h[1], h[2], h[3]);
    *(int4*)(p + PSTRIDE)     = make_int4(md[0], md[1], md[2], md[3]);
    *(int4*)(p + 2 * PSTRIDE) = make_int4(lo[0], lo[1], lo[2], lo[3]);
  }
}

// ---------------------------------------------------------------------------
// GEMM v3 (latency fix for the round-1 regression: MfmaUtil 7.6%, Occ 19.5%):
//  - KSPLIT=16 -> 1024 blocks = 4 blocks/CU (16 waves/CU TLP)
//  - A staged by global_load_lds dwordx4 (async DMA, no reg round-trip),
//    XOR-swizzled layout via PRE-SWIZZLED global source (dest stays linear);
//    fragment ds_read_b128 conflict-free (8-cycle minimum)
//  - B fragments -> 12 short8 regs loaded at iteration TOP (issued before the
//    A lds-loads so vmcnt waits for B never wait on A); ~200cy of A-read +
//    split VALU between issue and first MFMA use hides L2 latency
//  - fa rebuilt per mt (12 live frag regs, not 24) -> fits LB(256,4) @ <=128 VGPR
// Numerics identical to the round-0 passing kernel.
// ---------------------------------------------------------------------------
__global__ __launch_bounds__(256, 4) void gemm_k(const float* __restrict__ A,
                                                 const short* __restrict__ Bs,
                                                 float* __restrict__ Lp,
                                                 int atomic_mode) {
  __shared__ __align__(16) float As[2][BM * CHUNK];  // 2 x 16 KB
  const int tid = threadIdx.x;
  const int m_base = blockIdx.x * BM;
  const int k_base = blockIdx.y * KSLICE;
  float* Lout = Lp + (atomic_mode ? (size_t)0 : (size_t)blockIdx.y * NTOK * NEXP);

  const int lane = tid & 63;
  const int wave = tid >> 6;
  const int l15 = lane & 15;
  const int quad = lane >> 4;
  const int wm = wave * 32;

  // --- A staging geometry (global_load_lds: lane l -> ldsbase + l*16B) ---
  // slot S=(wave*4+j)*64+lane holds row = S>>3, swizzled colblk sw = S&7;
  // global colblk c = sw ^ (row&7) = (lane&7) ^ (lane>>3)  (j,wave drop out mod 8)
  const int rowp = wave * 32 + (lane >> 3);
  const int cblk = (lane & 7) ^ (lane >> 3);
  const float* gA0 = A + (size_t)(m_base + rowp) * HDIM + k_base + cblk * 4;

  auto stageA = [&](int i, int buf) {
#pragma unroll
    for (int j = 0; j < 4; ++j) {
      const float* src = gA0 + (size_t)(j * 8) * HDIM + i * CHUNK;
      __builtin_amdgcn_global_load_lds((gas_t)(const void*)src,
                                       (las_t)(void*)&As[buf][(wave * 4 + j) * 256],
                                       16, 0, 0);
    }
  };

  // --- B fragments: [chunk][part][expert=nt*16+l15][quad*8..] from L2 ---
  const short* bbase = Bs + (size_t)(k_base >> 5) * CSTRIDE + (size_t)l15 * 32 + quad * 8;
  short8 breg[12];
  auto loadB = [&](int i) {
    const short* bp = bbase + (size_t)i * CSTRIDE;
#pragma unroll
    for (int nt = 0; nt < 4; ++nt)
#pragma unroll
      for (int p = 0; p < 3; ++p)
        breg[nt * 3 + p] = *(const short8*)(bp + nt * 512 + p * PSTRIDE);
  };

  f32x4 acc[2][4];
#pragma unroll
  for (int mt = 0; mt < 2; ++mt)
#pragma unroll
    for (int nt = 0; nt < 4; ++nt) acc[mt][nt] = (f32x4){0.f, 0.f, 0.f, 0.f};

  stageA(0, 0);
  __syncthreads();  // compiler drains vmcnt before s_barrier -> As[0] valid

  for (int i = 0; i < NCHUNK; ++i) {
    const int buf = i & 1;
    loadB(i);                                  // B first: vmcnt waits skip A-lds
    if (i + 1 < NCHUNK) stageA(i + 1, buf ^ 1);

#pragma unroll
    for (int mt = 0; mt < 2; ++mt) {
      const int r = wm + mt * 16 + l15;
      const int rb = r * CHUNK;
      const int sw = r & 7;
      const float4 a0 = *(const float4*)&As[buf][rb + ((2 * quad) ^ sw) * 4];
      const float4 a1 = *(const float4*)&As[buf][rb + ((2 * quad + 1) ^ sw) * 4];
      const float f[8] = {a0.x, a0.y, a0.z, a0.w, a1.x, a1.y, a1.z, a1.w};
      int h[4], md[4], lo[4];
#pragma unroll
      for (int j = 0; j < 4; ++j) split2x3(f[2 * j], f[2 * j + 1], h[j], md[j], lo[j]);
      const short8 fh = pack_s8(h[0], h[1], h[2], h[3]);
      const short8 fm = pack_s8(md[0], md[1], md[2], md[3]);
      const short8 fl = pack_s8(lo[0], lo[1], lo[2], lo[3]);
#pragma unroll
      for (int nt = 0; nt < 4; ++nt) {
        const short8 bh = breg[nt * 3 + 0];
        const short8 bm = breg[nt * 3 + 1];
        const short8 bl = breg[nt * 3 + 2];
        f32x4 c = acc[mt][nt];
        c = __builtin_amdgcn_mfma_f32_16x16x32_bf16(fh, bh, c, 0, 0, 0);
        c = __builtin_amdgcn_mfma_f32_16x16x32_bf16(fh, bm, c, 0, 0, 0);
        c = __builtin_amdgcn_mfma_f32_16x16x32_bf16(fm, bh, c, 0, 0, 0);
        c = __builtin_amdgcn_mfma_f32_16x16x32_bf16(fh, bl, c, 0, 0, 0);
        c = __builtin_amdgcn_mfma_f32_16x16x32_bf16(fl, bh, c, 0, 0, 0);
        c = __builtin_amdgcn_mfma_f32_16x16x32_bf16(fm, bm, c, 0, 0, 0);
        acc[mt][nt] = c;
      }
    }
    // barrier: (a) all waves done reading As[buf] before it is re-staged in
    // i+1; (b) vmcnt(0) drain completes the As[buf^1] DMA issued above.
    __syncthreads();
  }

#pragma unroll
  for (int mt = 0; mt < 2; ++mt)
#pragma unroll
    for (int nt = 0; nt < 4; ++nt)
#pragma unroll
      for (int r = 0; r < 4; ++r) {
        const int m = m_base + wm + mt * 16 + quad * 4 + r;
        const int n = nt * 16 + l15;
        if (atomic_mode) atomicAdd(&Lout[(size_t)m * NEXP + n], acc[mt][nt][r]);
        else Lout[(size_t)m * NEXP + n] = acc[mt][nt][r];
      }
}

// ---------------------------------------------------------------------------
// Top-k router, wave-per-token (lane = expert). Unrolled 16-slice reduction.
// ---------------------------------------------------------------------------
__global__ __launch_bounds__(256) void topk_k(const float* __restrict__ Lp, int nsl,
                                              float* __restrict__ out,
                                              float* __restrict__ auxbuf) {
  __shared__ float sl[4][64];
  __shared__ float s_aux[128];  // [0:64) prob sums, [64:128) pick counts
  const int tid = threadIdx.x;
  const int wave = tid >> 6, lane = tid & 63;
  if (tid < 128) s_aux[tid] = 0.f;
  __syncthreads();

  for (int it = 0; it < TPW; ++it) {
    const int t = (blockIdx.x * 4 + wave) * TPW + it;
    float x = 0.f;
    if (nsl == KSPLIT) {
#pragma unroll
      for (int s = 0; s < KSPLIT; ++s)
        x += Lp[(size_t)s * (NTOK * NEXP) + (size_t)t * NEXP + lane];
    } else {
      for (int s = 0; s < nsl; ++s)
        x += Lp[(size_t)s * (NTOK * NEXP) + (size_t)t * NEXP + lane];
    }
    sl[wave][lane] = x;

    float mx = x;
#pragma unroll
    for (int off = 32; off >= 1; off >>= 1)
      mx = fmaxf(mx, __shfl_xor(mx, off, 64));
    const float e = __expf(x - mx);
    float ssum = e;
#pragma unroll
    for (int off = 32; off >= 1; off >>= 1) ssum += __shfl_xor(ssum, off, 64);
    const float prob = e / ssum;

    __syncthreads();  // sl visible (uniform barrier: same trip count all waves)

    int cnt = 0;
#pragma unroll
    for (int c = 0; c < 4; ++c) {
      const float4 v0 = *(const float4*)&sl[wave][c * 16 + 0];
      const float4 v1 = *(const float4*)&sl[wave][c * 16 + 4];
      const float4 v2 = *(const float4*)&sl[wave][c * 16 + 8];
      const float4 v3 = *(const float4*)&sl[wave][c * 16 + 12];
      const float xv[16] = {v0.x, v0.y, v0.z, v0.w, v1.x, v1.y, v1.z, v1.w,
                            v2.x, v2.y, v2.z, v2.w, v3.x, v3.y, v3.z, v3.w};
#pragma unroll
      for (int j = 0; j < 16; ++j) {
        const int jj = c * 16 + j;
        cnt += (xv[j] > x) || (xv[j] == x && jj < lane);
      }
    }

    float tp = (cnt < 8) ? prob : 0.f;
    float tsum = tp;
#pragma unroll
    for (int off = 32; off >= 1; off >>= 1) tsum += __shfl_xor(tsum, off, 64);

    const int dst = cnt << 2;  // ranks are a permutation -> collision-free
    const float pv = __uint_as_float(
        (unsigned)__builtin_amdgcn_ds_permute(dst, (int)__float_as_uint(prob)));
    const int pi = __builtin_amdgcn_ds_permute(dst, lane);
    if (lane < 8) {
      out[(size_t)t * 8 + lane] = pv / tsum;
      out[(size_t)NTOK * 8 + (size_t)t * 8 + lane] = (float)pi;
    }
    atomicAdd(&s_aux[lane], prob);
    if (cnt < 8) atomicAdd(&s_aux[64 + lane], 1.f);
  }
  __syncthreads();
  if (tid < 128) atomicAdd(&auxbuf[(blockIdx.x & 7) * 128 + tid], s_aux[tid]);
}

// aux = E * sum_e (count_e/(T*K)) * (sumprob_e/T), over 8 auxbuf copies
__global__ void aux_k(const float* __restrict__ auxbuf, float* __restrict__ out) {
  const int e = threadIdx.x;  // 64 threads
  float p = 0.f, f = 0.f;
#pragma unroll
  for (int c = 0; c < 8; ++c) {
    p += auxbuf[c * 128 + e];
    f += auxbuf[c * 128 + 64 + e];
  }
  p *= (1.f / (float)NTOK);
  f *= (1.f / ((float)NTOK * 8.f));
  float v = f * p;
#pragma unroll
  for (int off = 32; off >= 1; off >>= 1) v += __shfl_xor(v, off, 64);
  if (e == 0) out[2 * NTOK * 8] = 64.f * v;
}

extern "C" void kernel_launch(void* const* d_in, const int* in_sizes, int n_in,
                              void* d_out, int out_size, void* d_ws, size_t ws_size,
                              hipStream_t stream) {
  const float* hidden = (const float*)d_in[0];  // 8192 x 4096 fp32
  const float* gate = (const float*)d_in[1];    // 64 x 4096 fp32
  float* out = (float*)d_out;                   // [w 65536 | idx 65536 | aux 1]
  float* ws = (float*)d_ws;
  float* auxbuf = ws;                        // 8 copies x 128 floats
  short* Bs = (short*)(ws + AUXF);           // pre-split B, 1.5 MB
  float* slices = ws + SLICEOFF;             // KSPLIT x (8192*64) fp32 partials

  const size_t need = (size_t)SLICEOFF * 4 + (size_t)KSPLIT * NTOK * NEXP * 4;
  const int atomic_mode = (ws_size < need) ? 1 : 0;
  const int nsl = atomic_mode ? 1 : KSPLIT;

  if (atomic_mode)
    hipMemsetAsync(d_ws, 0, (size_t)SLICEOFF * 4 + (size_t)NTOK * NEXP * 4, stream);
  else
    hipMemsetAsync(d_ws, 0, (size_t)AUXF * 4, stream);

  bsplit_k<<<NEXP, 256, 0, stream>>>(gate, Bs);
  gemm_k<<<dim3(64, KSPLIT), 256, 0, stream>>>(hidden, Bs, slices, atomic_mode);
  topk_k<<<NTOK / (4 * TPW), 256, 0, stream>>>(slices, nsl, out, auxbuf);
  aux_k<<<1, 64, 0, stream>>>(auxbuf, out);
}